// Round 4
// baseline (352.098 us; speedup 1.0000x reference)
//
#include <hip/hip_runtime.h>

// Problem constants (B,T,C,H,Dh) = (4,2048,1024,16,64); M = B*T = 8192.
#define SEQ_T 2048
#define NBATCH 4
#define CDIM 1024
#define NHEAD 16
#define MROWS 8192      // NBATCH * SEQ_T
#define QKVC 3072       // 3*CDIM

typedef unsigned short u16;
typedef __bf16 bf16x8 __attribute__((ext_vector_type(8)));
typedef float f32x4 __attribute__((ext_vector_type(4)));
typedef unsigned uint32x4 __attribute__((ext_vector_type(4)));

__device__ __forceinline__ u16 f32_to_bf16(float f) {
  union { float f; unsigned int u; } v; v.f = f;
  unsigned int u = v.u;
  unsigned int r = ((u >> 16) & 1u) + 0x7fffu;   // round-to-nearest-even
  return (u16)((u + r) >> 16);
}

__device__ __forceinline__ void gload_lds16(const u16* g, u16* l) {
  __builtin_amdgcn_global_load_lds(
      (const __attribute__((address_space(1))) void*)g,
      (__attribute__((address_space(3))) void*)l, 16, 0, 0);
}

// ---------------------------------------------------------------- cast f32 -> bf16
__global__ __launch_bounds__(256) void cast_bf16_kernel(const float* __restrict__ in,
                                                        u16* __restrict__ out, int n4) {
  int i = blockIdx.x * 256 + threadIdx.x;
  if (i >= n4) return;
  float4 v = ((const float4*)in)[i];
  ushort4 o;
  o.x = f32_to_bf16(v.x); o.y = f32_to_bf16(v.y);
  o.z = f32_to_bf16(v.z); o.w = f32_to_bf16(v.w);
  ((ushort4*)out)[i] = o;
}

// ------------------------------------------- transpose + cast: out[c][r] = in[r][c]
__global__ void transpose_cast_kernel(const float* __restrict__ in, u16* __restrict__ out,
                                      int R, int Cc) {
  __shared__ float tile[32][33];
  int c0 = blockIdx.x * 32, r0 = blockIdx.y * 32;
  int tx = threadIdx.x, ty = threadIdx.y;   // 32 x 8
  #pragma unroll
  for (int i = 0; i < 32; i += 8)
    tile[ty + i][tx] = in[(size_t)(r0 + ty + i) * Cc + c0 + tx];
  __syncthreads();
  #pragma unroll
  for (int i = 0; i < 32; i += 8)
    out[(size_t)(c0 + ty + i) * R + r0 + tx] = f32_to_bf16(tile[tx][ty + i]);
}

// --------------------------------- V transpose: Vt[(b*H+h)*64+dv][t] = V[b][t][h*64+dv]
__global__ void transpose_v_kernel(const u16* __restrict__ QKV, u16* __restrict__ Vt) {
  __shared__ u16 tile[32][34];
  const int t0 = blockIdx.x * 32, d0 = blockIdx.y * 32;
  const int bh = blockIdx.z;
  const int b = bh >> 4, h = bh & 15;
  const int tx = threadIdx.x, ty = threadIdx.y;   // 32 x 8
  const u16* Vp = QKV + (size_t)b * SEQ_T * QKVC + 2 * CDIM + h * 64;
  #pragma unroll
  for (int i = 0; i < 32; i += 8)
    tile[ty + i][tx] = Vp[(size_t)(t0 + ty + i) * QKVC + d0 + tx];
  __syncthreads();
  u16* Op = Vt + ((size_t)bh * 64 + d0) * SEQ_T + t0;
  #pragma unroll
  for (int i = 0; i < 32; i += 8)
    Op[(size_t)(ty + i) * SEQ_T + tx] = tile[tx][ty + i];
}

// ---------------------------------------------------------------- bf16 MFMA GEMM
// C[M][N] = A[M][K] * Bt[N][K]^T.  128x128 tile, BK=32, 4 waves (2x2).
// QSCALE: multiply output columns < CDIM by 0.125*log2(e)  (folds the attention
// softmax scale into Q at the QKV-projection epilogue).
template <typename OT, bool QSCALE>
__global__ __launch_bounds__(256)
void gemm_bt_kernel(const u16* __restrict__ A, const u16* __restrict__ Bt,
                    OT* __restrict__ C, int N, int K) {
  __shared__ u16 lA[128 * 32];
  __shared__ u16 lB[128 * 32];
  const int tid = threadIdx.x;
  const int lane = tid & 63, wid = tid >> 6;
  const int wm = wid >> 1, wn = wid & 1;
  const int l15 = lane & 15, lhi = lane >> 4;
  const int row0 = blockIdx.x * 128, col0 = blockIdx.y * 128;
  const int sr = lane >> 2;
  const int sc = (lane & 3) * 8;
  const int ca = wid * 2;

  f32x4 acc[4][4] = {};

  for (int k0 = 0; k0 < K; k0 += 32) {
    #pragma unroll
    for (int c = 0; c < 2; ++c) {
      const int ch = ca + c;
      gload_lds16(A  + (size_t)(row0 + ch * 16 + sr) * K + k0 + sc, &lA[ch * 512]);
      gload_lds16(Bt + (size_t)(col0 + ch * 16 + sr) * K + k0 + sc, &lB[ch * 512]);
    }
    __syncthreads();
    bf16x8 af[4], bfr[4];
    #pragma unroll
    for (int mt = 0; mt < 4; ++mt)
      af[mt] = *(const bf16x8*)&lA[(wm * 64 + mt * 16 + l15) * 32 + lhi * 8];
    #pragma unroll
    for (int nt = 0; nt < 4; ++nt)
      bfr[nt] = *(const bf16x8*)&lB[(wn * 64 + nt * 16 + l15) * 32 + lhi * 8];
    #pragma unroll
    for (int mt = 0; mt < 4; ++mt)
      #pragma unroll
      for (int nt = 0; nt < 4; ++nt)
        acc[mt][nt] = __builtin_amdgcn_mfma_f32_16x16x32_bf16(af[mt], bfr[nt], acc[mt][nt], 0, 0, 0);
    __syncthreads();
  }

  #pragma unroll
  for (int mt = 0; mt < 4; ++mt)
    #pragma unroll
    for (int nt = 0; nt < 4; ++nt)
      #pragma unroll
      for (int r = 0; r < 4; ++r) {
        const int rr = row0 + wm * 64 + mt * 16 + lhi * 4 + r;
        const int cc = col0 + wn * 64 + nt * 16 + l15;
        float v = acc[mt][nt][r];
        if (QSCALE && cc < CDIM) v *= 0.18033688011f;   // 0.125 * log2(e)
        if constexpr (sizeof(OT) == 2) C[(size_t)rr * N + cc] = f32_to_bf16(v);
        else                           C[(size_t)rr * N + cc] = v;
      }
}

// ---------------------------------------------------------------- flash attention
// Balanced paired jobs (j, 127-j) per wave; K double-buffered, V single-buffered
// issue-early; Q pre-scaled by 0.125*log2e in the QKV GEMM -> p = exp2(s) direct,
// per-lane partial row-sums reduced once at the epilogue; P^T -> PA fragment via
// IN-REGISTER 4x4 lane-group transpose (cvt_pk_bf16 + permlane32/16_swap), no LDS.
// XCD-aware block mapping clusters all 16 blocks of one (b,h) on one XCD so K/V
// (512 KB) stays L2-resident.
template <bool DOMASK>
__device__ __forceinline__ void attn_step(const bf16x8 (&qf)[2],
                                          const bf16x8 (&kf)[2][2],
                                          const bf16x8 (&vb)[4],
                                          f32x4 (&acc)[4], float& lsum,
                                          int l15, int lhi, int kv0, int qg) {
  f32x4 st[2];
  #pragma unroll
  for (int t = 0; t < 2; ++t) {
    f32x4 z = {0.f, 0.f, 0.f, 0.f};
    z = __builtin_amdgcn_mfma_f32_16x16x32_bf16(kf[t][0], qf[0], z, 0, 0, 0);
    z = __builtin_amdgcn_mfma_f32_16x16x32_bf16(kf[t][1], qf[1], z, 0, 0, 0);
    st[t] = z;
  }
  #pragma unroll
  for (int t = 0; t < 2; ++t)
    #pragma unroll
    for (int r = 0; r < 4; ++r) {
      float sv = st[t][r];                       // Q pre-scaled: log2-domain score
      if (DOMASK) {
        const int kvg = kv0 + t * 16 + lhi * 4 + r;
        sv = (kvg > qg) ? -__builtin_inff() : sv;
      }
      const float p = exp2f(sv);
      st[t][r] = p;
      lsum += p;
    }
  // In-register P^T -> PA transpose among the 4 lane-groups sharing l15.
  // Source: lane group g holds P[q=l15][kv0 + t*16 + g*4 + r].
  // Target: lane group g' needs pa32[m] = bf16x2 P[q][kv0 + g'*8 + 2m .. +1].
  unsigned c00, c01, c10, c11;
  asm("v_cvt_pk_bf16_f32 %0, %1, %2" : "=v"(c00) : "v"(st[0][0]), "v"(st[0][1]));
  asm("v_cvt_pk_bf16_f32 %0, %1, %2" : "=v"(c01) : "v"(st[0][2]), "v"(st[0][3]));
  asm("v_cvt_pk_bf16_f32 %0, %1, %2" : "=v"(c10) : "v"(st[1][0]), "v"(st[1][1]));
  asm("v_cvt_pk_bf16_f32 %0, %1, %2" : "=v"(c11) : "v"(st[1][2]), "v"(st[1][3]));
  asm("v_permlane32_swap_b32 %0, %1" : "+v"(c00), "+v"(c10));   // rows: [g0t0,g1t0,g0t1,g1t1] / [g2t0,g3t0,g2t1,g3t1]
  asm("v_permlane32_swap_b32 %0, %1" : "+v"(c01), "+v"(c11));
  asm("v_permlane16_swap_b32 %0, %1" : "+v"(c00), "+v"(c10));   // -> pa32[0]/pa32[2]
  asm("v_permlane16_swap_b32 %0, %1" : "+v"(c01), "+v"(c11));   // -> pa32[1]/pa32[3]
  uint32x4 pw; pw[0] = c00; pw[1] = c01; pw[2] = c10; pw[3] = c11;
  const bf16x8 pa = __builtin_bit_cast(bf16x8, pw);
  #pragma unroll
  for (int d = 0; d < 4; ++d)
    acc[d] = __builtin_amdgcn_mfma_f32_16x16x32_bf16(pa, vb[d], acc[d], 0, 0, 0);
}

__global__ __launch_bounds__(256, 4) void attn_kernel(const u16* __restrict__ QKV,
                                                      const u16* __restrict__ Vt,
                                                      u16* __restrict__ Y) {
  const int tid = threadIdx.x, lane = tid & 63, wid = tid >> 6;
  const int l15 = lane & 15, lhi = lane >> 4;
  // XCD-aware decode: id = xcd + 8*k + 128*(bh>>3), xcd = bh&7.
  const int id = blockIdx.x;
  const int xcd = id & 7, k = (id >> 3) & 15, hi3 = id >> 7;
  const int bh = hi3 * 8 + xcd;
  const int b = bh >> 4, h = bh & 15;
  const int pa = k * 4 + wid;                    // pair index 0..63
  const int qA0 = pa * 16, qB0 = (127 - pa) * 16;
  const int nchA = pa / 2 + 1, nchB = (127 - pa) / 2 + 1;
  const size_t base = (size_t)b * SEQ_T * QKVC;
  const u16* Qp  = QKV + base + h * 64;
  const u16* Kp  = QKV + base + CDIM + h * 64;
  const u16* Vtp = Vt + (size_t)bh * 64 * SEQ_T;

  bf16x8 qfA[2], qfB[2];
  #pragma unroll
  for (int i = 0; i < 2; ++i) {
    qfA[i] = *(const bf16x8*)(Qp + (size_t)(qA0 + l15) * QKVC + i * 32 + lhi * 8);
    qfB[i] = *(const bf16x8*)(Qp + (size_t)(qB0 + l15) * QKVC + i * 32 + lhi * 8);
  }
  const int qgA = qA0 + l15, qgB = qB0 + l15;

  f32x4 accA[4] = {}, accB[4] = {};
  float lsA = 0.f, lsB = 0.f;

  bf16x8 kfa[2][2], kfb[2][2], vb[4];

#define LOADK(KV0, kf)                                                          \
  {                                                                             \
    const int _kv = (KV0);                                                      \
    _Pragma("unroll") for (int t = 0; t < 2; ++t)                               \
      _Pragma("unroll") for (int i = 0; i < 2; ++i)                             \
        kf[t][i] = *(const bf16x8*)(Kp + (size_t)(_kv + t * 16 + l15) * QKVC + i * 32 + lhi * 8); \
  }
#define LOADV(KV0)                                                              \
  {                                                                             \
    const int _kv = (KV0);                                                      \
    _Pragma("unroll") for (int d = 0; d < 4; ++d)                               \
      vb[d] = *(const bf16x8*)(Vtp + (size_t)(d * 16 + l15) * SEQ_T + _kv + lhi * 8); \
  }

#define STEPBODY(kfc, kfn)                                                      \
  {                                                                             \
    if (ic + 1 < nchB) LOADK((ic + 1) * 32, kfn);                               \
    const int kv0 = ic * 32;                                                    \
    if (ic == nchB - 1)                                                         \
      attn_step<true>(qfB, kfc, vb, accB, lsB, l15, lhi, kv0, qgB);             \
    else                                                                        \
      attn_step<false>(qfB, kfc, vb, accB, lsB, l15, lhi, kv0, qgB);            \
    if (ic < nchA) {                                                            \
      if (ic == nchA - 1)                                                       \
        attn_step<true>(qfA, kfc, vb, accA, lsA, l15, lhi, kv0, qgA);           \
      else                                                                      \
        attn_step<false>(qfA, kfc, vb, accA, lsA, l15, lhi, kv0, qgA);          \
    }                                                                           \
    ++ic;                                                                       \
    if (ic < nchB) LOADV(ic * 32);                                              \
  }

  int ic = 0;
  LOADK(0, kfa);
  LOADV(0);
  while (true) {
    STEPBODY(kfa, kfb);
    if (ic >= nchB) break;
    STEPBODY(kfb, kfa);
    if (ic >= nchB) break;
  }
#undef LOADK
#undef LOADV
#undef STEPBODY

  // epilogue: reduce per-lane partial row-sums, divide, store
  lsA += __shfl_xor(lsA, 16); lsA += __shfl_xor(lsA, 32);
  lsB += __shfl_xor(lsB, 16); lsB += __shfl_xor(lsB, 32);

  u16* Yp = Y + (size_t)b * SEQ_T * CDIM + h * 64;
  #pragma unroll
  for (int r = 0; r < 4; ++r) {
    const float lrA = __shfl(lsA, lhi * 4 + r, 64);
    const float lrB = __shfl(lsB, lhi * 4 + r, 64);
    const float ivA = 1.0f / lrA, ivB = 1.0f / lrB;
    #pragma unroll
    for (int d = 0; d < 4; ++d) {
      Yp[(size_t)(qA0 + lhi * 4 + r) * CDIM + d * 16 + l15] = f32_to_bf16(accA[d][r] * ivA);
      Yp[(size_t)(qB0 + lhi * 4 + r) * CDIM + d * 16 + l15] = f32_to_bf16(accB[d][r] * ivB);
    }
  }
}

// ---------------------------------------------------------------- launch
extern "C" void kernel_launch(void* const* d_in, const int* in_sizes, int n_in,
                              void* d_out, int out_size, void* d_ws, size_t ws_size,
                              hipStream_t stream) {
  const float* x      = (const float*)d_in[0];
  const float* w_qkv  = (const float*)d_in[1];
  const float* w_proj = (const float*)d_in[2];
  float* out = (float*)d_out;

  u16* Xb  = (u16*)d_ws;                                // 8192*1024 bf16
  u16* Wqt = Xb  + (size_t)MROWS * CDIM;                // 3072*1024
  u16* Wpt = Wqt + (size_t)QKVC * CDIM;                 // 1024*1024
  u16* QKV = Wpt + (size_t)CDIM * CDIM;                 // 8192*3072
  u16* Yb  = QKV + (size_t)MROWS * QKVC;                // 8192*1024
  u16* Vt  = Yb  + (size_t)MROWS * CDIM;                // 64*64*2048 (V transposed)

  // casts / transposes
  cast_bf16_kernel<<<(MROWS * CDIM / 4 + 255) / 256, 256, 0, stream>>>(x, Xb, MROWS * CDIM / 4);
  transpose_cast_kernel<<<dim3(QKVC / 32, CDIM / 32), dim3(32, 8), 0, stream>>>(w_qkv, Wqt, CDIM, QKVC);
  transpose_cast_kernel<<<dim3(CDIM / 32, CDIM / 32), dim3(32, 8), 0, stream>>>(w_proj, Wpt, CDIM, CDIM);

  // qkv = x @ w_qkv  (bf16 out; Q columns pre-scaled by 0.125*log2e)
  gemm_bt_kernel<u16, true><<<dim3(MROWS / 128, QKVC / 128), 256, 0, stream>>>(Xb, Wqt, QKV, QKVC, CDIM);

  // V transpose for contiguous PV B-fragments
  transpose_v_kernel<<<dim3(SEQ_T / 32, 2, NBATCH * NHEAD), dim3(32, 8), 0, stream>>>(QKV, Vt);

  // attention (balanced paired q-jobs, XCD-clustered)
  attn_kernel<<<1024, 256, 0, stream>>>(QKV, Vt, Yb);

  // out = y @ w_proj  (f32 out)
  gemm_bt_kernel<float, false><<<dim3(MROWS / 128, CDIM / 128), 256, 0, stream>>>(Yb, Wpt, out, CDIM, CDIM);
}

// Round 5
// 258.400 us; speedup vs baseline: 1.3626x; 1.3626x over previous
//
#include <hip/hip_runtime.h>

// Problem constants (B,T,C,H,Dh) = (4,2048,1024,16,64); M = B*T = 8192.
#define SEQ_T 2048
#define NBATCH 4
#define CDIM 1024
#define NHEAD 16
#define MROWS 8192      // NBATCH * SEQ_T
#define QKVC 3072       // 3*CDIM

typedef unsigned short u16;
typedef __bf16 bf16x8 __attribute__((ext_vector_type(8)));
typedef float f32x4 __attribute__((ext_vector_type(4)));
typedef unsigned uint32x4 __attribute__((ext_vector_type(4)));

__device__ __forceinline__ u16 f32_to_bf16(float f) {
  union { float f; unsigned int u; } v; v.f = f;
  unsigned int u = v.u;
  unsigned int r = ((u >> 16) & 1u) + 0x7fffu;   // round-to-nearest-even
  return (u16)((u + r) >> 16);
}

__device__ __forceinline__ void gload_lds16(const u16* g, u16* l) {
  __builtin_amdgcn_global_load_lds(
      (const __attribute__((address_space(1))) void*)g,
      (__attribute__((address_space(3))) void*)l, 16, 0, 0);
}

// ---------------------------------------------------------------- cast f32 -> bf16
__global__ __launch_bounds__(256) void cast_bf16_kernel(const float* __restrict__ in,
                                                        u16* __restrict__ out, int n4) {
  int i = blockIdx.x * 256 + threadIdx.x;
  if (i >= n4) return;
  float4 v = ((const float4*)in)[i];
  ushort4 o;
  o.x = f32_to_bf16(v.x); o.y = f32_to_bf16(v.y);
  o.z = f32_to_bf16(v.z); o.w = f32_to_bf16(v.w);
  ((ushort4*)out)[i] = o;
}

// ------------------------------------------- transpose + cast: out[c][r] = in[r][c]
__global__ void transpose_cast_kernel(const float* __restrict__ in, u16* __restrict__ out,
                                      int R, int Cc) {
  __shared__ float tile[32][33];
  int c0 = blockIdx.x * 32, r0 = blockIdx.y * 32;
  int tx = threadIdx.x, ty = threadIdx.y;   // 32 x 8
  #pragma unroll
  for (int i = 0; i < 32; i += 8)
    tile[ty + i][tx] = in[(size_t)(r0 + ty + i) * Cc + c0 + tx];
  __syncthreads();
  #pragma unroll
  for (int i = 0; i < 32; i += 8)
    out[(size_t)(c0 + ty + i) * R + r0 + tx] = f32_to_bf16(tile[tx][ty + i]);
}

// ---------------------------------------------------------------- K repack
// Kc[bh][t/16][i][kv&15][lhi*8+j] : per 16-kv tile two 1KB halves (d<32 | d>=32).
// Fragment load becomes lane -> base + lane*16 (fully coalesced 1KB).
__global__ __launch_bounds__(256) void repack_k_kernel(const u16* __restrict__ QKV,
                                                       u16* __restrict__ Kc) {
  const int kvt32 = blockIdx.x, bh = blockIdx.y;
  const int b = bh >> 4, h = bh & 15;
  const int tid = threadIdx.x;
  const int half = tid >> 7, r = (tid >> 3) & 15, c8 = tid & 7;
  const int t = kvt32 * 32 + half * 16 + r;
  const bf16x8 v = *(const bf16x8*)(QKV + (size_t)b * SEQ_T * QKVC + (size_t)t * QKVC +
                                    CDIM + h * 64 + c8 * 8);
  // dcol = c8*8+j  ->  i = c8>>2, within = (c8&3)*8+j
  *(bf16x8*)(Kc + (size_t)bh * 131072 + (size_t)(kvt32 * 2 + half) * 1024 +
             (c8 >> 2) * 512 + r * 32 + (c8 & 3) * 8) = v;
}

// ---------------------------------------------------------------- V repack
// Vc[bh][t/32][dv>>4][dv&15][kv&31] : per 32-kv tile four 1KB d-tiles.
// vb[d] fragment load: lane -> base + d*1024B + lane*16 (fully coalesced).
__global__ void repack_v_kernel(const u16* __restrict__ QKV, u16* __restrict__ Vc) {
  __shared__ u16 tile[32][34];
  const int t0 = blockIdx.x * 32, d0 = blockIdx.y * 32;
  const int bh = blockIdx.z;
  const int b = bh >> 4, h = bh & 15;
  const int tx = threadIdx.x, ty = threadIdx.y;   // 32 x 8
  const u16* Vp = QKV + (size_t)b * SEQ_T * QKVC + 2 * CDIM + h * 64 + d0;
  #pragma unroll
  for (int i = 0; i < 32; i += 8)
    tile[ty + i][tx] = Vp[(size_t)(t0 + ty + i) * QKVC + tx];   // tile[a][bc] = V[t0+a][d0+bc]
  __syncthreads();
  const int tid = ty * 32 + tx;
  if (tid < 128) {
    const int bc = tid >> 2, ag = tid & 3;
    ushort8_t: ;
    union { u16 u[8]; bf16x8 v; } o;
    #pragma unroll
    for (int j = 0; j < 8; ++j) o.u[j] = tile[ag * 8 + j][bc];
    const int dv = d0 + bc;
    *(bf16x8*)(Vc + (size_t)bh * 131072 + (size_t)(t0 >> 5) * 2048 +
               (dv >> 4) * 512 + (dv & 15) * 32 + ag * 8) = o.v;
  }
}

// ---------------------------------------------------------------- bf16 MFMA GEMM
// C[M][N] = A[M][K] * Bt[N][K]^T.  128x128 tile, BK=32, 4 waves (2x2).
// QSCALE: multiply output columns < CDIM by 0.125*log2(e).
template <typename OT, bool QSCALE>
__global__ __launch_bounds__(256)
void gemm_bt_kernel(const u16* __restrict__ A, const u16* __restrict__ Bt,
                    OT* __restrict__ C, int N, int K) {
  __shared__ u16 lA[128 * 32];
  __shared__ u16 lB[128 * 32];
  const int tid = threadIdx.x;
  const int lane = tid & 63, wid = tid >> 6;
  const int wm = wid >> 1, wn = wid & 1;
  const int l15 = lane & 15, lhi = lane >> 4;
  const int row0 = blockIdx.x * 128, col0 = blockIdx.y * 128;
  const int sr = lane >> 2;
  const int sc = (lane & 3) * 8;
  const int ca = wid * 2;

  f32x4 acc[4][4] = {};

  for (int k0 = 0; k0 < K; k0 += 32) {
    #pragma unroll
    for (int c = 0; c < 2; ++c) {
      const int ch = ca + c;
      gload_lds16(A  + (size_t)(row0 + ch * 16 + sr) * K + k0 + sc, &lA[ch * 512]);
      gload_lds16(Bt + (size_t)(col0 + ch * 16 + sr) * K + k0 + sc, &lB[ch * 512]);
    }
    __syncthreads();
    bf16x8 af[4], bfr[4];
    #pragma unroll
    for (int mt = 0; mt < 4; ++mt)
      af[mt] = *(const bf16x8*)&lA[(wm * 64 + mt * 16 + l15) * 32 + lhi * 8];
    #pragma unroll
    for (int nt = 0; nt < 4; ++nt)
      bfr[nt] = *(const bf16x8*)&lB[(wn * 64 + nt * 16 + l15) * 32 + lhi * 8];
    #pragma unroll
    for (int mt = 0; mt < 4; ++mt)
      #pragma unroll
      for (int nt = 0; nt < 4; ++nt)
        acc[mt][nt] = __builtin_amdgcn_mfma_f32_16x16x32_bf16(af[mt], bfr[nt], acc[mt][nt], 0, 0, 0);
    __syncthreads();
  }

  #pragma unroll
  for (int mt = 0; mt < 4; ++mt)
    #pragma unroll
    for (int nt = 0; nt < 4; ++nt)
      #pragma unroll
      for (int r = 0; r < 4; ++r) {
        const int rr = row0 + wm * 64 + mt * 16 + lhi * 4 + r;
        const int cc = col0 + wn * 64 + nt * 16 + l15;
        float v = acc[mt][nt][r];
        if (QSCALE && cc < CDIM) v *= 0.18033688011f;   // 0.125 * log2(e)
        if constexpr (sizeof(OT) == 2) C[(size_t)rr * N + cc] = f32_to_bf16(v);
        else                           C[(size_t)rr * N + cc] = v;
      }
}

// ---------------------------------------------------------------- flash attention
// Same structure as round 4 (paired jobs, K dbuf, in-register P transpose,
// XCD clustering) but ALL K/V loads now hit pre-blocked fragment-ordered tiles:
// each kf/vb load is one 1KB fully-contiguous wave transaction (8 full lines)
// instead of 16 scattered 64B segments -> attacks the TA/L1 address-pipe wall.
template <bool DOMASK>
__device__ __forceinline__ void attn_step(const bf16x8 (&qf)[2],
                                          const bf16x8 (&kf)[2][2],
                                          const bf16x8 (&vb)[4],
                                          f32x4 (&acc)[4], float& lsum,
                                          int l15, int lhi, int kv0, int qg) {
  f32x4 st[2];
  #pragma unroll
  for (int t = 0; t < 2; ++t) {
    f32x4 z = {0.f, 0.f, 0.f, 0.f};
    z = __builtin_amdgcn_mfma_f32_16x16x32_bf16(kf[t][0], qf[0], z, 0, 0, 0);
    z = __builtin_amdgcn_mfma_f32_16x16x32_bf16(kf[t][1], qf[1], z, 0, 0, 0);
    st[t] = z;
  }
  #pragma unroll
  for (int t = 0; t < 2; ++t)
    #pragma unroll
    for (int r = 0; r < 4; ++r) {
      float sv = st[t][r];                       // Q pre-scaled: log2-domain score
      if (DOMASK) {
        const int kvg = kv0 + t * 16 + lhi * 4 + r;
        sv = (kvg > qg) ? -__builtin_inff() : sv;
      }
      const float p = exp2f(sv);
      st[t][r] = p;
      lsum += p;
    }
  // In-register P^T -> PA transpose among the 4 lane-groups sharing l15.
  unsigned c00, c01, c10, c11;
  asm("v_cvt_pk_bf16_f32 %0, %1, %2" : "=v"(c00) : "v"(st[0][0]), "v"(st[0][1]));
  asm("v_cvt_pk_bf16_f32 %0, %1, %2" : "=v"(c01) : "v"(st[0][2]), "v"(st[0][3]));
  asm("v_cvt_pk_bf16_f32 %0, %1, %2" : "=v"(c10) : "v"(st[1][0]), "v"(st[1][1]));
  asm("v_cvt_pk_bf16_f32 %0, %1, %2" : "=v"(c11) : "v"(st[1][2]), "v"(st[1][3]));
  asm("v_permlane32_swap_b32 %0, %1" : "+v"(c00), "+v"(c10));
  asm("v_permlane32_swap_b32 %0, %1" : "+v"(c01), "+v"(c11));
  asm("v_permlane16_swap_b32 %0, %1" : "+v"(c00), "+v"(c10));
  asm("v_permlane16_swap_b32 %0, %1" : "+v"(c01), "+v"(c11));
  uint32x4 pw; pw[0] = c00; pw[1] = c01; pw[2] = c10; pw[3] = c11;
  const bf16x8 pa = __builtin_bit_cast(bf16x8, pw);
  #pragma unroll
  for (int d = 0; d < 4; ++d)
    acc[d] = __builtin_amdgcn_mfma_f32_16x16x32_bf16(pa, vb[d], acc[d], 0, 0, 0);
}

__global__ __launch_bounds__(256, 4) void attn_kernel(const u16* __restrict__ QKV,
                                                      const u16* __restrict__ Kc,
                                                      const u16* __restrict__ Vc,
                                                      u16* __restrict__ Y) {
  const int tid = threadIdx.x, lane = tid & 63, wid = tid >> 6;
  const int l15 = lane & 15, lhi = lane >> 4;
  const int lofs = l15 * 32 + lhi * 8;           // lane*16B within a 1KB tile
  // XCD-aware decode: id = xcd + 8*k + 128*(bh>>3), xcd = bh&7.
  const int id = blockIdx.x;
  const int xcd = id & 7, k = (id >> 3) & 15, hi3 = id >> 7;
  const int bh = hi3 * 8 + xcd;
  const int b = bh >> 4, h = bh & 15;
  const int pa = k * 4 + wid;                    // pair index 0..63
  const int qA0 = pa * 16, qB0 = (127 - pa) * 16;
  const int nchA = pa / 2 + 1, nchB = (127 - pa) / 2 + 1;
  const size_t base = (size_t)b * SEQ_T * QKVC;
  const u16* Qp  = QKV + base + h * 64;
  const u16* Kbh = Kc + (size_t)bh * 131072;
  const u16* Vbh = Vc + (size_t)bh * 131072;

  bf16x8 qfA[2], qfB[2];
  #pragma unroll
  for (int i = 0; i < 2; ++i) {
    qfA[i] = *(const bf16x8*)(Qp + (size_t)(qA0 + l15) * QKVC + i * 32 + lhi * 8);
    qfB[i] = *(const bf16x8*)(Qp + (size_t)(qB0 + l15) * QKVC + i * 32 + lhi * 8);
  }
  const int qgA = qA0 + l15, qgB = qB0 + l15;

  f32x4 accA[4] = {}, accB[4] = {};
  float lsA = 0.f, lsB = 0.f;

  bf16x8 kfa[2][2], kfb[2][2], vb[4];

#define LOADK(IC, kf)                                                           \
  {                                                                             \
    const u16* _p = Kbh + (size_t)(IC) * 2048 + lofs;                           \
    _Pragma("unroll") for (int t = 0; t < 2; ++t)                               \
      _Pragma("unroll") for (int i = 0; i < 2; ++i)                             \
        kf[t][i] = *(const bf16x8*)(_p + t * 1024 + i * 512);                   \
  }
#define LOADV(IC)                                                               \
  {                                                                             \
    const u16* _p = Vbh + (size_t)(IC) * 2048 + lofs;                           \
    _Pragma("unroll") for (int d = 0; d < 4; ++d)                               \
      vb[d] = *(const bf16x8*)(_p + d * 512);                                   \
  }

#define STEPBODY(kfc, kfn)                                                      \
  {                                                                             \
    if (ic + 1 < nchB) LOADK(ic + 1, kfn);                                      \
    const int kv0 = ic * 32;                                                    \
    if (ic == nchB - 1)                                                         \
      attn_step<true>(qfB, kfc, vb, accB, lsB, l15, lhi, kv0, qgB);             \
    else                                                                        \
      attn_step<false>(qfB, kfc, vb, accB, lsB, l15, lhi, kv0, qgB);            \
    if (ic < nchA) {                                                            \
      if (ic == nchA - 1)                                                       \
        attn_step<true>(qfA, kfc, vb, accA, lsA, l15, lhi, kv0, qgA);           \
      else                                                                      \
        attn_step<false>(qfA, kfc, vb, accA, lsA, l15, lhi, kv0, qgA);          \
    }                                                                           \
    ++ic;                                                                       \
    if (ic < nchB) LOADV(ic);                                                   \
  }

  int ic = 0;
  LOADK(0, kfa);
  LOADV(0);
  while (true) {
    STEPBODY(kfa, kfb);
    if (ic >= nchB) break;
    STEPBODY(kfb, kfa);
    if (ic >= nchB) break;
  }
#undef LOADK
#undef LOADV
#undef STEPBODY

  // epilogue: reduce per-lane partial row-sums, divide, store
  lsA += __shfl_xor(lsA, 16); lsA += __shfl_xor(lsA, 32);
  lsB += __shfl_xor(lsB, 16); lsB += __shfl_xor(lsB, 32);

  u16* Yp = Y + (size_t)b * SEQ_T * CDIM + h * 64;
  #pragma unroll
  for (int r = 0; r < 4; ++r) {
    const float lrA = __shfl(lsA, lhi * 4 + r, 64);
    const float lrB = __shfl(lsB, lhi * 4 + r, 64);
    const float ivA = 1.0f / lrA, ivB = 1.0f / lrB;
    #pragma unroll
    for (int d = 0; d < 4; ++d) {
      Yp[(size_t)(qA0 + lhi * 4 + r) * CDIM + d * 16 + l15] = f32_to_bf16(accA[d][r] * ivA);
      Yp[(size_t)(qB0 + lhi * 4 + r) * CDIM + d * 16 + l15] = f32_to_bf16(accB[d][r] * ivB);
    }
  }
}

// ---------------------------------------------------------------- launch
extern "C" void kernel_launch(void* const* d_in, const int* in_sizes, int n_in,
                              void* d_out, int out_size, void* d_ws, size_t ws_size,
                              hipStream_t stream) {
  const float* x      = (const float*)d_in[0];
  const float* w_qkv  = (const float*)d_in[1];
  const float* w_proj = (const float*)d_in[2];
  float* out = (float*)d_out;

  u16* Xb  = (u16*)d_ws;                                // 8192*1024 bf16 (dead after GEMM1)
  u16* Wqt = Xb  + (size_t)MROWS * CDIM;                // 3072*1024
  u16* Wpt = Wqt + (size_t)QKVC * CDIM;                 // 1024*1024
  u16* QKV = Wpt + (size_t)CDIM * CDIM;                 // 8192*3072
  u16* Yb  = QKV + (size_t)MROWS * QKVC;                // 8192*1024
  u16* Vc  = Yb  + (size_t)MROWS * CDIM;                // 64*131072 (blocked V)
  u16* Kc  = Xb;                                        // 64*131072 (blocked K, aliases Xb)

  // casts / transposes
  cast_bf16_kernel<<<(MROWS * CDIM / 4 + 255) / 256, 256, 0, stream>>>(x, Xb, MROWS * CDIM / 4);
  transpose_cast_kernel<<<dim3(QKVC / 32, CDIM / 32), dim3(32, 8), 0, stream>>>(w_qkv, Wqt, CDIM, QKVC);
  transpose_cast_kernel<<<dim3(CDIM / 32, CDIM / 32), dim3(32, 8), 0, stream>>>(w_proj, Wpt, CDIM, CDIM);

  // qkv = x @ w_qkv  (bf16 out; Q columns pre-scaled by 0.125*log2e)
  gemm_bt_kernel<u16, true><<<dim3(MROWS / 128, QKVC / 128), 256, 0, stream>>>(Xb, Wqt, QKV, QKVC, CDIM);

  // K/V repack into fragment-ordered 1KB tiles (Kc overwrites Xb - safe after GEMM1)
  repack_k_kernel<<<dim3(SEQ_T / 32, NBATCH * NHEAD), 256, 0, stream>>>(QKV, Kc);
  repack_v_kernel<<<dim3(SEQ_T / 32, 2, NBATCH * NHEAD), dim3(32, 8), 0, stream>>>(QKV, Vc);

  // attention (balanced paired q-jobs, XCD-clustered, coalesced fragment loads)
  attn_kernel<<<1024, 256, 0, stream>>>(QKV, Kc, Vc, Yb);

  // out = y @ w_proj  (f32 out)
  gemm_bt_kernel<float, false><<<dim3(MROWS / 128, CDIM / 128), 256, 0, stream>>>(Yb, Wpt, out, CDIM, CDIM);
}